// Round 13
// baseline (138.585 us; speedup 1.0000x reference)
//
#include <hip/hip_runtime.h>
#include <stdint.h>

#define NXS 8192
#define HS  1024

typedef __attribute__((ext_vector_type(8))) short short8;
typedef __attribute__((ext_vector_type(4))) float f32x4;

__device__ __forceinline__ float bf2f(uint32_t b) {
    union { uint32_t u; float f; } c; c.u = b << 16; return c.f;
}
__device__ __forceinline__ uint16_t f2bf(float f) {
    union { float f; uint32_t u; } c; c.f = f;
    return (uint16_t)((c.u + 0x7fffu + ((c.u >> 16) & 1u)) >> 16);
}
// fast tanh: 1 - 2/(e^{2x}+1); |err| ~1e-5 << bf16 quantum; clamp +-15.
__device__ __forceinline__ float fast_tanh(float x) {
    float xc = fminf(fmaxf(x, -15.f), 15.f);
    return 1.f - __fdividef(2.f, __expf(2.f * xc) + 1.f);
}
__device__ __forceinline__ void async_cp16(const void* g, void* l) {
    __builtin_amdgcn_global_load_lds(
        (const __attribute__((address_space(1))) void*)g,
        (__attribute__((address_space(3))) void*)l,
        16, 0, 0);
}
// raw barrier with compiler memory fences (no waitcnt drain)
__device__ __forceinline__ void mem_barrier() {
    asm volatile("" ::: "memory");
    __builtin_amdgcn_s_barrier();
    asm volatile("" ::: "memory");
}

// ---- K01: merged prep (unchanged) ----
__global__ __launch_bounds__(256) void k01(
    const float* __restrict__ x, const float* __restrict__ W1,
    const float* __restrict__ b1, const float* __restrict__ W2,
    const float* __restrict__ b3, uint16_t* __restrict__ Z1,
    uint16_t* __restrict__ Bp1, uint16_t* __restrict__ Bp2,
    uint16_t* __restrict__ W1T, float* __restrict__ out)
{
    __shared__ float xs[8][8];
    const int b = blockIdx.x, t = threadIdx.x;
    if (b < 1024) {
        const int n0 = b * 8;
        if (t < 64) xs[t >> 3][t & 7] = x[n0 * 8 + t];
        const int j = t * 4;
        float w[4][8];
#pragma unroll
        for (int c = 0; c < 4; ++c) {
            float4 w0 = *(const float4*)(W1 + (j + c) * 8);
            float4 w1 = *(const float4*)(W1 + (j + c) * 8 + 4);
            w[c][0] = w0.x; w[c][1] = w0.y; w[c][2] = w0.z; w[c][3] = w0.w;
            w[c][4] = w1.x; w[c][5] = w1.y; w[c][6] = w1.z; w[c][7] = w1.w;
        }
        float4 bb = *(const float4*)(b1 + j);
        const float bv[4] = {bb.x, bb.y, bb.z, bb.w};
        __syncthreads();
#pragma unroll
        for (int s = 0; s < 8; ++s) {
            ushort4 o;
            uint16_t* op = (uint16_t*)&o;
#pragma unroll
            for (int c = 0; c < 4; ++c) {
                float sum = bv[c];
#pragma unroll
                for (int k = 0; k < 8; ++k) sum += xs[s][k] * w[c][k];
                op[c] = f2bf(fast_tanh(sum));
            }
            *(ushort4*)(Z1 + (size_t)(n0 + s) * HS + j) = o;
        }
    } else if (b < 1536) {
        const int tid = (b - 1024) * 256 + t;            // 0..131071
        const int l = tid & 63, c = (tid >> 6) & 31, g = tid >> 11;
        const int lr = l & 15, lq = l >> 4;
        const float* src = W2 + (size_t)(g * 16 + lr) * HS + c * 32 + lq * 8;
        float4 a0 = *(const float4*)src;
        float4 a1 = *(const float4*)(src + 4);
        uint16_t o[8];
        o[0] = f2bf(a0.x); o[1] = f2bf(a0.y); o[2] = f2bf(a0.z); o[3] = f2bf(a0.w);
        o[4] = f2bf(a1.x); o[5] = f2bf(a1.y); o[6] = f2bf(a1.z); o[7] = f2bf(a1.w);
        *(ushort4*)(Bp1 + (size_t)tid * 8)     = *(ushort4*)&o[0];
        *(ushort4*)(Bp1 + (size_t)tid * 8 + 4) = *(ushort4*)&o[4];
    } else if (b < 2048) {
        const int tid = (b - 1536) * 256 + t;
        const int l = tid & 63, c = (tid >> 6) & 31, g = tid >> 11;
        const int lr = l & 15, lq = l >> 4;
        uint16_t o[8];
#pragma unroll
        for (int j2 = 0; j2 < 8; ++j2)
            o[j2] = f2bf(W2[(size_t)(c * 32 + lq * 8 + j2) * HS + g * 16 + lr]);
        *(ushort4*)(Bp2 + (size_t)tid * 8)     = *(ushort4*)&o[0];
        *(ushort4*)(Bp2 + (size_t)tid * 8 + 4) = *(ushort4*)&o[4];
    } else if (b < 2336) {
        const int idx = (b - 2048) * 256 + t;            // 0..73727
        out[idx] = (idx < NXS) ? b3[0] : 0.f;
    } else {
        const int idx = (b - 2336) * 256 + t;            // 0..16383
        const int r = idx >> 10, cc = idx & 1023;
        W1T[idx] = (r < 8) ? f2bf(W1[cc * 8 + r]) : (uint16_t)0;
    }
}

// -------- GEMM v2: LDS-traffic-halved structure.
// R10 probe showed the old loop moves 48KB/block-step through LDS (~580cy
// floor) vs 154cy MFMA issue -> LDS-BW-bound, which is why all schedule
// variants tied. Fix: B fragments load global(L2)->VGPR directly (4 coalesced
// 1KB loads/wave/step, double-buffered bX/bY via 2x unroll); only A staged to
// LDS (quad-buffer 4x8KB, depth-2 gload_lds). LDS/block-step: 48KB -> 24KB.
// Sync: prologue-only hand vmcnt(4) (proven constant); in-loop raw s_barrier
// + mem clobbers, NO hand waitcnt. Correctness invariant: B(c) is issued
// AFTER stageA(c+1) at step c-1, and the compiler's mandatory wait before
// MFMA's use of B(c) at step c retires (in-order vmcnt) stageA(c+1) before
// the end-of-step-c barrier -> buf(c+1) is globally visible at step c+1.
// Tile 128x128, 4 waves (2x2), BK=32, wave-tile 64x64 (acc[4][4]).
// MODE 0: C = Z1 @ W2^T (Bp1); epilogue: tanh -> V (bf16), y atomics
// MODE 1: C = U = V @ W2 (Bp2); fused MFMA dydx epilogue via W1T
template <int MODE>
__global__ __launch_bounds__(256, 2) void gemm_k(
    const uint16_t* __restrict__ A, const uint16_t* __restrict__ Bp,
    const float* __restrict__ bias, const float* __restrict__ W3,
    uint16_t* __restrict__ Out, float* __restrict__ yOut,
    const uint16_t* __restrict__ Z1, const uint16_t* __restrict__ W1T,
    float* __restrict__ dOut)
{
    // loop: 4 A-bufs x 8KB = 32KB; MODE1 epilogue 128x136 u16 = 34.8KB
    __shared__ __attribute__((aligned(16))) uint16_t smem[17408];
    const int t = threadIdx.x;
    const int wave = t >> 6, lane = t & 63;
    const int lq = lane >> 4, lr = lane & 15;
    const int wr = wave >> 1, wc = wave & 1;
    const int rowBase = blockIdx.x * 128;
    const int colBase = blockIdx.y * 128;

    // A staging: 512 segs of 16B per step (128 rows x 4 slots), 2/thread.
    // Source slot pre-swizzled q = (s&3)^((row>>1)&3) (R10-proven, 0 confl).
    const uint16_t* gA0;
    const uint16_t* gA1;
    {
        int s0 = t,       r0 = s0 >> 2, q0 = (s0 & 3) ^ ((r0 >> 1) & 3);
        int s1 = t + 256, r1 = s1 >> 2, q1 = (s1 & 3) ^ ((r1 >> 1) & 3);
        gA0 = A + (size_t)(rowBase + r0) * HS + q0 * 8;
        gA1 = A + (size_t)(rowBase + r1) * HS + q1 * 8;
    }
    const int ldsA0 = t * 16;          // byte offset within an 8KB buffer
    const int ldsA1 = t * 16 + 4096;

    // B fragment streams: wave wc owns groups colBase/16 + wc*4 + tj;
    // frag for K-chunk c at pB[tj] + c*512 (coalesced 1KB per wave-load).
    const uint16_t* pB[4];
#pragma unroll
    for (int tj = 0; tj < 4; ++tj)
        pB[tj] = Bp + ((size_t)(colBase >> 4) + wc * 4 + tj) * 16384
                    + (size_t)lane * 8;

    // MODE0 epilogue scalars FIRST (oldest vmem, retired by prologue wait)
    float cB[4], cW[4]; int cCol[4];
    if (MODE == 0) {
#pragma unroll
        for (int tj = 0; tj < 4; ++tj) {
            cCol[tj] = colBase + wc * 64 + tj * 16 + lr;
            cB[tj] = bias[cCol[tj]];
            cW[tj] = W3[cCol[tj]];
        }
    }

    f32x4 acc[4][4] = {};
    short8 bX[4], bY[4];

    // prologue: stageA(0)->buf0, stageA(1)->buf1, then bX = B(0)
    async_cp16(gA0,      (char*)smem + ldsA0);
    async_cp16(gA1,      (char*)smem + ldsA1);
    async_cp16(gA0 + 32, (char*)smem + 8192 + ldsA0);
    async_cp16(gA1 + 32, (char*)smem + 8192 + ldsA1);
    asm volatile("" ::: "memory");           // pin B after stage issue
#pragma unroll
    for (int tj = 0; tj < 4; ++tj)
        bX[tj] = *(const short8*)(pB[tj]);
    // retire scalars + stageA(0) + stageA(1); bX stays in flight
    asm volatile("s_waitcnt vmcnt(4)" ::: "memory");
    __builtin_amdgcn_s_barrier();
    asm volatile("" ::: "memory");

#define COMPUTE(bufByte, breg)                                               \
    {                                                                        \
        const uint16_t* pA_ = (const uint16_t*)((const char*)smem + (bufByte)); \
        short8 af_[4];                                                       \
        _Pragma("unroll")                                                    \
        for (int ti_ = 0; ti_ < 4; ++ti_) {                                  \
            int ar_ = wr * 64 + ti_ * 16 + lr;                               \
            af_[ti_] = *(const short8*)(pA_ + ar_ * 32                       \
                        + ((lq ^ ((ar_ >> 1) & 3)) << 3));                   \
        }                                                                    \
        _Pragma("unroll")                                                    \
        for (int ti_ = 0; ti_ < 4; ++ti_)                                    \
            _Pragma("unroll")                                                \
            for (int tj_ = 0; tj_ < 4; ++tj_)                                \
                acc[ti_][tj_] = __builtin_amdgcn_mfma_f32_16x16x32_bf16(     \
                    af_[ti_], breg[tj_], acc[ti_][tj_], 0, 0, 0);            \
    }

#pragma unroll 1
    for (int i = 0; i < 16; ++i) {
        const int c = 2 * i;
        const int bEven = (i & 1) * 16384;          // buf (c  &3) byte base
        const int bOdd  = bEven + 8192;             // buf (c+1&3)
        const int bNx2  = ((i & 1) ^ 1) * 16384;    // buf (c+2&3)
        const int bNx3  = bNx2 + 8192;              // buf (c+3&3)

        // ---- even step c: stage A(c+2), load bY=B(c+1), compute buf(c), bX
        if (c + 2 < 32) {
            async_cp16(gA0 + (c + 2) * 32, (char*)smem + bNx2 + ldsA0);
            async_cp16(gA1 + (c + 2) * 32, (char*)smem + bNx2 + ldsA1);
            asm volatile("" ::: "memory");
        }
        if (c + 1 < 32) {
#pragma unroll
            for (int tj = 0; tj < 4; ++tj)
                bY[tj] = *(const short8*)(pB[tj] + (c + 1) * 512);
        }
        COMPUTE(bEven, bX)
        mem_barrier();

        // ---- odd step c+1: stage A(c+3), load bX=B(c+2), compute buf(c+1), bY
        if (c + 3 < 32) {
            async_cp16(gA0 + (c + 3) * 32, (char*)smem + bNx3 + ldsA0);
            async_cp16(gA1 + (c + 3) * 32, (char*)smem + bNx3 + ldsA1);
            asm volatile("" ::: "memory");
        }
        if (c + 2 < 32) {
#pragma unroll
            for (int tj = 0; tj < 4; ++tj)
                bX[tj] = *(const short8*)(pB[tj] + (c + 2) * 512);
        }
        COMPUTE(bOdd, bY)
        mem_barrier();
    }
#undef COMPUTE

    if (MODE == 0) {
#pragma unroll
        for (int ti = 0; ti < 4; ++ti) {
#pragma unroll
            for (int r = 0; r < 4; ++r) {
                int row = rowBase + wr * 64 + ti * 16 + lq * 4 + r;
                float ys = 0.f;
#pragma unroll
                for (int tj = 0; tj < 4; ++tj) {
                    float z2 = fast_tanh(acc[ti][tj][r] + cB[tj]);
                    ys += z2 * cW[tj];
                    Out[(size_t)row * HS + cCol[tj]] = f2bf((1.f - z2 * z2) * cW[tj]);
                }
                ys += __shfl_xor(ys, 1); ys += __shfl_xor(ys, 2);
                ys += __shfl_xor(ys, 4); ys += __shfl_xor(ys, 8);
                if (lr == 0) atomicAdd(&yOut[row], ys);
            }
        }
    } else {
        // c = U*(1-z1^2) -> LDS [128 rows][stride 136 u16] (loop fully
        // retired: last stageA consumed at step 31, all reads pre-barrier)
#pragma unroll
        for (int ti = 0; ti < 4; ++ti)
#pragma unroll
            for (int r = 0; r < 4; ++r) {
                int rowl = wr * 64 + ti * 16 + lq * 4 + r;
                const size_t zrow = (size_t)(rowBase + rowl) * HS + colBase;
#pragma unroll
                for (int tj = 0; tj < 4; ++tj) {
                    int coll = wc * 64 + tj * 16 + lr;
                    float z1 = bf2f(Z1[zrow + coll]);
                    smem[rowl * 136 + coll] =
                        f2bf(acc[ti][tj][r] * (1.f - z1 * z1));
                }
            }
        __syncthreads();
        f32x4 dd[2] = {};
#pragma unroll
        for (int h = 0; h < 2; ++h)
#pragma unroll
            for (int kb = 0; kb < 4; ++kb) {
                short8 aF = *(const short8*)(smem + (wave * 32 + h * 16 + lr) * 136
                                             + kb * 32 + lq * 8);
                short8 bF = *(const short8*)(W1T + (size_t)lr * HS + colBase
                                             + kb * 32 + lq * 8);
                dd[h] = __builtin_amdgcn_mfma_f32_16x16x32_bf16(aF, bF, dd[h], 0, 0, 0);
            }
        if (lr < 8) {
#pragma unroll
            for (int h = 0; h < 2; ++h) {
                int row = rowBase + wave * 32 + h * 16 + lq * 4;
#pragma unroll
                for (int rg = 0; rg < 4; ++rg)
                    atomicAdd(&dOut[(size_t)lr * NXS + row + rg], dd[h][rg]);
            }
        }
    }
}

extern "C" void kernel_launch(void* const* d_in, const int* in_sizes, int n_in,
                              void* d_out, int out_size, void* d_ws, size_t ws_size,
                              hipStream_t stream) {
    (void)in_sizes; (void)n_in; (void)out_size; (void)ws_size;
    const float* x  = (const float*)d_in[0];
    const float* W1 = (const float*)d_in[1];
    const float* b1 = (const float*)d_in[2];
    const float* W2 = (const float*)d_in[3];
    const float* b2 = (const float*)d_in[4];
    const float* W3 = (const float*)d_in[5];
    const float* b3 = (const float*)d_in[6];
    float* out = (float*)d_out;

    char* ws = (char*)d_ws;
    // ws layout:
    //   [0, 16MB)     Z1 bf16        [16MB, 32MB)  V bf16
    //   [32MB, 34MB)  Bp1            [34MB, 36MB)  Bp2
    //   [36MB, +32KB) W1T
    uint16_t* Z1  = (uint16_t*)(ws);
    uint16_t* V   = (uint16_t*)(ws + (size_t)16 * 1024 * 1024);
    uint16_t* Bp1 = (uint16_t*)(ws + (size_t)32 * 1024 * 1024);
    uint16_t* Bp2 = (uint16_t*)(ws + (size_t)34 * 1024 * 1024);
    uint16_t* W1T = (uint16_t*)(ws + (size_t)36 * 1024 * 1024);

    k01<<<2400, 256, 0, stream>>>(x, W1, b1, W2, b3, Z1, Bp1, Bp2, W1T, out);
    gemm_k<0><<<dim3(NXS / 128, HS / 128), 256, 0, stream>>>(
        Z1, Bp1, b2, W3, V, out, nullptr, nullptr, nullptr);
    gemm_k<1><<<dim3(NXS / 128, HS / 128), 256, 0, stream>>>(
        V, Bp2, nullptr, nullptr, nullptr, nullptr, Z1, W1T, out + NXS);
}

// Round 14
// 132.062 us; speedup vs baseline: 1.0494x; 1.0494x over previous
//
#include <hip/hip_runtime.h>
#include <stdint.h>

#define NXS 8192
#define HS  1024

typedef __attribute__((ext_vector_type(8))) short short8;
typedef __attribute__((ext_vector_type(4))) float f32x4;

__device__ __forceinline__ float bf2f(uint32_t b) {
    union { uint32_t u; float f; } c; c.u = b << 16; return c.f;
}
__device__ __forceinline__ uint16_t f2bf(float f) {
    union { float f; uint32_t u; } c; c.f = f;
    return (uint16_t)((c.u + 0x7fffu + ((c.u >> 16) & 1u)) >> 16);
}
// fast tanh: 1 - 2/(e^{2x}+1); |err| ~1e-5 << bf16 quantum; clamp +-15.
__device__ __forceinline__ float fast_tanh(float x) {
    float xc = fminf(fmaxf(x, -15.f), 15.f);
    return 1.f - __fdividef(2.f, __expf(2.f * xc) + 1.f);
}
__device__ __forceinline__ void async_cp16(const void* g, void* l) {
    __builtin_amdgcn_global_load_lds(
        (const __attribute__((address_space(1))) void*)g,
        (__attribute__((address_space(3))) void*)l,
        16, 0, 0);
}

// ---- K01: merged prep (unchanged) ----
__global__ __launch_bounds__(256) void k01(
    const float* __restrict__ x, const float* __restrict__ W1,
    const float* __restrict__ b1, const float* __restrict__ W2,
    const float* __restrict__ b3, uint16_t* __restrict__ Z1,
    uint16_t* __restrict__ Bp1, uint16_t* __restrict__ Bp2,
    uint16_t* __restrict__ W1T, float* __restrict__ out)
{
    __shared__ float xs[8][8];
    const int b = blockIdx.x, t = threadIdx.x;
    if (b < 1024) {
        const int n0 = b * 8;
        if (t < 64) xs[t >> 3][t & 7] = x[n0 * 8 + t];
        const int j = t * 4;
        float w[4][8];
#pragma unroll
        for (int c = 0; c < 4; ++c) {
            float4 w0 = *(const float4*)(W1 + (j + c) * 8);
            float4 w1 = *(const float4*)(W1 + (j + c) * 8 + 4);
            w[c][0] = w0.x; w[c][1] = w0.y; w[c][2] = w0.z; w[c][3] = w0.w;
            w[c][4] = w1.x; w[c][5] = w1.y; w[c][6] = w1.z; w[c][7] = w1.w;
        }
        float4 bb = *(const float4*)(b1 + j);
        const float bv[4] = {bb.x, bb.y, bb.z, bb.w};
        __syncthreads();
#pragma unroll
        for (int s = 0; s < 8; ++s) {
            ushort4 o;
            uint16_t* op = (uint16_t*)&o;
#pragma unroll
            for (int c = 0; c < 4; ++c) {
                float sum = bv[c];
#pragma unroll
                for (int k = 0; k < 8; ++k) sum += xs[s][k] * w[c][k];
                op[c] = f2bf(fast_tanh(sum));
            }
            *(ushort4*)(Z1 + (size_t)(n0 + s) * HS + j) = o;
        }
    } else if (b < 1536) {
        const int tid = (b - 1024) * 256 + t;            // 0..131071
        const int l = tid & 63, c = (tid >> 6) & 31, g = tid >> 11;
        const int lr = l & 15, lq = l >> 4;
        const float* src = W2 + (size_t)(g * 16 + lr) * HS + c * 32 + lq * 8;
        float4 a0 = *(const float4*)src;
        float4 a1 = *(const float4*)(src + 4);
        uint16_t o[8];
        o[0] = f2bf(a0.x); o[1] = f2bf(a0.y); o[2] = f2bf(a0.z); o[3] = f2bf(a0.w);
        o[4] = f2bf(a1.x); o[5] = f2bf(a1.y); o[6] = f2bf(a1.z); o[7] = f2bf(a1.w);
        *(ushort4*)(Bp1 + (size_t)tid * 8)     = *(ushort4*)&o[0];
        *(ushort4*)(Bp1 + (size_t)tid * 8 + 4) = *(ushort4*)&o[4];
    } else if (b < 2048) {
        const int tid = (b - 1536) * 256 + t;
        const int l = tid & 63, c = (tid >> 6) & 31, g = tid >> 11;
        const int lr = l & 15, lq = l >> 4;
        uint16_t o[8];
#pragma unroll
        for (int j2 = 0; j2 < 8; ++j2)
            o[j2] = f2bf(W2[(size_t)(c * 32 + lq * 8 + j2) * HS + g * 16 + lr]);
        *(ushort4*)(Bp2 + (size_t)tid * 8)     = *(ushort4*)&o[0];
        *(ushort4*)(Bp2 + (size_t)tid * 8 + 4) = *(ushort4*)&o[4];
    } else if (b < 2336) {
        const int idx = (b - 2048) * 256 + t;            // 0..73727
        out[idx] = (idx < NXS) ? b3[0] : 0.f;
    } else {
        const int idx = (b - 2336) * 256 + t;            // 0..16383
        const int r = idx >> 10, cc = idx & 1023;
        W1T[idx] = (r < 8) ? f2bf(W1[cc * 8 + r]) : (uint16_t)0;
    }
}

// -------- GEMM: R10 production config VERBATIM (the session's best
// candidate, never measured standalone): 128x128 tile, 4 waves (2x2),
// BK=32, TRIPLE-buffered LDS, counted-vmcnt schedule.
//   step c: issue stage(c+2) [4 gload_lds/thread] -> ds_read + 16 MFMA/wave
//   on buf[c%3] -> vmcnt(4) (retire stage(c+1) only; stage(c+2) stays in
//   flight across the barrier) -> raw s_barrier. Peel c>=30 -> vmcnt(0).
// MODE0 epilogue scalars (bias/W3) hoisted before the prologue (oldest
// vmem, retired by the first wait -> vmcnt accounting stays exact).
// No setprio (R12 A/B: regressed). No vmcnt(8)-class deep pipelines
// (3/3 container failures). No B-direct-VGPR (R13: re-exposed latency).
// R10 probe counters: MfmaUtil 26%, VALUBusy 35%, stall ~39%, FETCH = A+B
// exactly, conflicts 0, ~26us/GEMM @ 660 TF.
template <int MODE>
__global__ __launch_bounds__(256, 2) void gemm_k(
    const uint16_t* __restrict__ A, const uint16_t* __restrict__ Bp,
    const float* __restrict__ bias, const float* __restrict__ W3,
    uint16_t* __restrict__ Out, float* __restrict__ yOut,
    const uint16_t* __restrict__ Z1, const uint16_t* __restrict__ W1T,
    float* __restrict__ dOut)
{
    __shared__ __attribute__((aligned(16))) uint16_t smem[24576];  // 48 KB
    const int t = threadIdx.x;
    const int wave = t >> 6, lane = t & 63;
    const int lq = lane >> 4, lr = lane & 15;
    const int wr = wave >> 1, wc = wave & 1;
    const int rowBase = blockIdx.x * 128;
    const int colBase = blockIdx.y * 128;

    // staging sources
    const uint16_t* gA0;
    const uint16_t* gA1;
    {
        int s0 = t,       r0 = s0 >> 2, q0 = (s0 & 3) ^ ((r0 >> 1) & 3);
        int s1 = t + 256, r1 = s1 >> 2, q1 = (s1 & 3) ^ ((r1 >> 1) & 3);
        gA0 = A + (size_t)(rowBase + r0) * HS + q0 * 8;
        gA1 = A + (size_t)(rowBase + r1) * HS + q1 * 8;
    }
    const uint16_t* gB0;
    const uint16_t* gB1;
    {
        int s0 = t, s1 = t + 256;
        gB0 = Bp + ((size_t)(colBase >> 4) + (s0 >> 6)) * 16384 + (size_t)(s0 & 63) * 8;
        gB1 = Bp + ((size_t)(colBase >> 4) + (s1 >> 6)) * 16384 + (size_t)(s1 & 63) * 8;
    }
    const int ldsA0 = t * 16;
    const int ldsA1 = t * 16 + 4096;
    const int ldsB0 = t * 16 + 8192;
    const int ldsB1 = t * 16 + 12288;

    // MODE0 epilogue scalars FIRST (oldest vmem, retired by first wait)
    float cB[4], cW[4]; int cCol[4];
    if (MODE == 0) {
#pragma unroll
        for (int tj = 0; tj < 4; ++tj) {
            cCol[tj] = colBase + wc * 64 + tj * 16 + lr;
            cB[tj] = bias[cCol[tj]];
            cW[tj] = W3[cCol[tj]];
        }
    }

    f32x4 acc[4][4] = {};

    // prologue: stage step 0 -> buf0, step 1 -> buf1
    async_cp16(gA0,        (char*)smem + ldsA0);
    async_cp16(gA1,        (char*)smem + ldsA1);
    async_cp16(gB0,        (char*)smem + ldsB0);
    async_cp16(gB1,        (char*)smem + ldsB1);
    async_cp16(gA0 + 32,   (char*)smem + 16384 + ldsA0);
    async_cp16(gA1 + 32,   (char*)smem + 16384 + ldsA1);
    async_cp16(gB0 + 512,  (char*)smem + 16384 + ldsB0);
    async_cp16(gB1 + 512,  (char*)smem + 16384 + ldsB1);
    gA0 += 64; gA1 += 64; gB0 += 1024; gB1 += 1024;
    asm volatile("s_waitcnt vmcnt(4)" ::: "memory");
    __builtin_amdgcn_s_barrier();

    int rb = 0, wb = 2;
#pragma unroll 1
    for (int c = 0; c < 32; ++c) {
        if (c < 30) {
            char* d = (char*)smem + wb * 16384;
            async_cp16(gA0, d + ldsA0);
            async_cp16(gA1, d + ldsA1);
            async_cp16(gB0, d + ldsB0);
            async_cp16(gB1, d + ldsB1);
            gA0 += 32; gA1 += 32; gB0 += 512; gB1 += 512;
            asm volatile("" ::: "memory");
        }
        const uint16_t* pA  = smem + rb * 8192;
        const uint16_t* pBl = pA + 4096;
        short8 bfrag[4];
#pragma unroll
        for (int tj = 0; tj < 4; ++tj)
            bfrag[tj] = *(const short8*)(pBl + (((wc << 2) + tj) * 64 + lane) * 8);
        short8 af[4];
#pragma unroll
        for (int ti = 0; ti < 4; ++ti) {
            int ar = wr * 64 + ti * 16 + lr;
            af[ti] = *(const short8*)(pA + ar * 32
                      + ((lq ^ ((ar >> 1) & 3)) << 3));
        }
#pragma unroll
        for (int ti = 0; ti < 4; ++ti)
#pragma unroll
            for (int tj = 0; tj < 4; ++tj)
                acc[ti][tj] = __builtin_amdgcn_mfma_f32_16x16x32_bf16(
                    af[ti], bfrag[tj], acc[ti][tj], 0, 0, 0);
        if (c < 30) {
            asm volatile("s_waitcnt vmcnt(4)" ::: "memory");
        } else {
            asm volatile("s_waitcnt vmcnt(0)" ::: "memory");
        }
        __builtin_amdgcn_s_barrier();
        rb = (rb == 2) ? 0 : rb + 1;
        wb = (wb == 2) ? 0 : wb + 1;
    }

    if (MODE == 0) {
#pragma unroll
        for (int ti = 0; ti < 4; ++ti) {
#pragma unroll
            for (int r = 0; r < 4; ++r) {
                int row = rowBase + wr * 64 + ti * 16 + lq * 4 + r;
                float ys = 0.f;
#pragma unroll
                for (int tj = 0; tj < 4; ++tj) {
                    float z2 = fast_tanh(acc[ti][tj][r] + cB[tj]);
                    ys += z2 * cW[tj];
                    Out[(size_t)row * HS + cCol[tj]] = f2bf((1.f - z2 * z2) * cW[tj]);
                }
                ys += __shfl_xor(ys, 1); ys += __shfl_xor(ys, 2);
                ys += __shfl_xor(ys, 4); ys += __shfl_xor(ys, 8);
                if (lr == 0) atomicAdd(&yOut[row], ys);
            }
        }
    } else {
        __builtin_amdgcn_sched_barrier(0);  // fence epilogue vmem below waits
        // c = U*(1-z1^2) -> LDS [128 rows][stride 136 u16]
#pragma unroll
        for (int ti = 0; ti < 4; ++ti)
#pragma unroll
            for (int r = 0; r < 4; ++r) {
                int rowl = wr * 64 + ti * 16 + lq * 4 + r;
                const size_t zrow = (size_t)(rowBase + rowl) * HS + colBase;
#pragma unroll
                for (int tj = 0; tj < 4; ++tj) {
                    int coll = wc * 64 + tj * 16 + lr;
                    float z1 = bf2f(Z1[zrow + coll]);
                    smem[rowl * 136 + coll] =
                        f2bf(acc[ti][tj][r] * (1.f - z1 * z1));
                }
            }
        __syncthreads();
        f32x4 dd[2] = {};
#pragma unroll
        for (int h = 0; h < 2; ++h)
#pragma unroll
            for (int kb = 0; kb < 4; ++kb) {
                short8 aF = *(const short8*)(smem + (wave * 32 + h * 16 + lr) * 136
                                             + kb * 32 + lq * 8);
                short8 bF = *(const short8*)(W1T + (size_t)lr * HS + colBase
                                             + kb * 32 + lq * 8);
                dd[h] = __builtin_amdgcn_mfma_f32_16x16x32_bf16(aF, bF, dd[h], 0, 0, 0);
            }
        if (lr < 8) {
#pragma unroll
            for (int h = 0; h < 2; ++h) {
                int row = rowBase + wave * 32 + h * 16 + lq * 4;
#pragma unroll
                for (int rg = 0; rg < 4; ++rg)
                    atomicAdd(&dOut[(size_t)lr * NXS + row + rg], dd[h][rg]);
            }
        }
    }
}

extern "C" void kernel_launch(void* const* d_in, const int* in_sizes, int n_in,
                              void* d_out, int out_size, void* d_ws, size_t ws_size,
                              hipStream_t stream) {
    (void)in_sizes; (void)n_in; (void)out_size; (void)ws_size;
    const float* x  = (const float*)d_in[0];
    const float* W1 = (const float*)d_in[1];
    const float* b1 = (const float*)d_in[2];
    const float* W2 = (const float*)d_in[3];
    const float* b2 = (const float*)d_in[4];
    const float* W3 = (const float*)d_in[5];
    const float* b3 = (const float*)d_in[6];
    float* out = (float*)d_out;

    char* ws = (char*)d_ws;
    // ws layout:
    //   [0, 16MB)     Z1 bf16        [16MB, 32MB)  V bf16
    //   [32MB, 34MB)  Bp1            [34MB, 36MB)  Bp2
    //   [36MB, +32KB) W1T
    uint16_t* Z1  = (uint16_t*)(ws);
    uint16_t* V   = (uint16_t*)(ws + (size_t)16 * 1024 * 1024);
    uint16_t* Bp1 = (uint16_t*)(ws + (size_t)32 * 1024 * 1024);
    uint16_t* Bp2 = (uint16_t*)(ws + (size_t)34 * 1024 * 1024);
    uint16_t* W1T = (uint16_t*)(ws + (size_t)36 * 1024 * 1024);

    k01<<<2400, 256, 0, stream>>>(x, W1, b1, W2, b3, Z1, Bp1, Bp2, W1T, out);
    gemm_k<0><<<dim3(NXS / 128, HS / 128), 256, 0, stream>>>(
        Z1, Bp1, b2, W3, V, out, nullptr, nullptr, nullptr);
    gemm_k<1><<<dim3(NXS / 128, HS / 128), 256, 0, stream>>>(
        V, Bp2, nullptr, nullptr, nullptr, nullptr, Z1, W1T, out + NXS);
}

// Round 15
// 131.217 us; speedup vs baseline: 1.0562x; 1.0064x over previous
//
#include <hip/hip_runtime.h>
#include <stdint.h>

#define NXS 8192
#define HS  1024

typedef __attribute__((ext_vector_type(8))) short short8;
typedef __attribute__((ext_vector_type(4))) float f32x4;

__device__ __forceinline__ float bf2f(uint32_t b) {
    union { uint32_t u; float f; } c; c.u = b << 16; return c.f;
}
__device__ __forceinline__ uint16_t f2bf(float f) {
    union { float f; uint32_t u; } c; c.f = f;
    return (uint16_t)((c.u + 0x7fffu + ((c.u >> 16) & 1u)) >> 16);
}
// fast tanh: 1 - 2/(e^{2x}+1); |err| ~1e-5 << bf16 quantum; clamp +-15.
__device__ __forceinline__ float fast_tanh(float x) {
    float xc = fminf(fmaxf(x, -15.f), 15.f);
    return 1.f - __fdividef(2.f, __expf(2.f * xc) + 1.f);
}
__device__ __forceinline__ void async_cp16(const void* g, void* l) {
    __builtin_amdgcn_global_load_lds(
        (const __attribute__((address_space(1))) void*)g,
        (__attribute__((address_space(3))) void*)l,
        16, 0, 0);
}

// ---- K01: merged prep. Z1 section now 16 samples/block (512 blocks):
// halves per-block W1 reload redundancy + launch tail vs 8/block.
// [0,512):      Z1 = tanh(x@W1^T+b1), 16 samples/block
// [512,1024):   pack Bp1 (W2 row-major fragments)
// [1024,1536):  pack Bp2 (W2^T fragments)
// [1536,1824):  init out: y = b3, dydx = 0
// [1824,1888):  W1T[16][1024] bf16 (rows 8..15 zero)
__global__ __launch_bounds__(256) void k01(
    const float* __restrict__ x, const float* __restrict__ W1,
    const float* __restrict__ b1, const float* __restrict__ W2,
    const float* __restrict__ b3, uint16_t* __restrict__ Z1,
    uint16_t* __restrict__ Bp1, uint16_t* __restrict__ Bp2,
    uint16_t* __restrict__ W1T, float* __restrict__ out)
{
    __shared__ float xs[16][8];
    const int b = blockIdx.x, t = threadIdx.x;
    if (b < 512) {
        const int n0 = b * 16;
        if (t < 128) xs[t >> 3][t & 7] = x[n0 * 8 + t];
        const int j = t * 4;
        float w[4][8];
#pragma unroll
        for (int c = 0; c < 4; ++c) {
            float4 w0 = *(const float4*)(W1 + (j + c) * 8);
            float4 w1 = *(const float4*)(W1 + (j + c) * 8 + 4);
            w[c][0] = w0.x; w[c][1] = w0.y; w[c][2] = w0.z; w[c][3] = w0.w;
            w[c][4] = w1.x; w[c][5] = w1.y; w[c][6] = w1.z; w[c][7] = w1.w;
        }
        float4 bb = *(const float4*)(b1 + j);
        const float bv[4] = {bb.x, bb.y, bb.z, bb.w};
        __syncthreads();
#pragma unroll
        for (int s = 0; s < 16; ++s) {
            ushort4 o;
            uint16_t* op = (uint16_t*)&o;
#pragma unroll
            for (int c = 0; c < 4; ++c) {
                float sum = bv[c];
#pragma unroll
                for (int k = 0; k < 8; ++k) sum += xs[s][k] * w[c][k];
                op[c] = f2bf(fast_tanh(sum));
            }
            *(ushort4*)(Z1 + (size_t)(n0 + s) * HS + j) = o;
        }
    } else if (b < 1024) {
        const int tid = (b - 512) * 256 + t;             // 0..131071
        const int l = tid & 63, c = (tid >> 6) & 31, g = tid >> 11;
        const int lr = l & 15, lq = l >> 4;
        const float* src = W2 + (size_t)(g * 16 + lr) * HS + c * 32 + lq * 8;
        float4 a0 = *(const float4*)src;
        float4 a1 = *(const float4*)(src + 4);
        uint16_t o[8];
        o[0] = f2bf(a0.x); o[1] = f2bf(a0.y); o[2] = f2bf(a0.z); o[3] = f2bf(a0.w);
        o[4] = f2bf(a1.x); o[5] = f2bf(a1.y); o[6] = f2bf(a1.z); o[7] = f2bf(a1.w);
        *(ushort4*)(Bp1 + (size_t)tid * 8)     = *(ushort4*)&o[0];
        *(ushort4*)(Bp1 + (size_t)tid * 8 + 4) = *(ushort4*)&o[4];
    } else if (b < 1536) {
        const int tid = (b - 1024) * 256 + t;
        const int l = tid & 63, c = (tid >> 6) & 31, g = tid >> 11;
        const int lr = l & 15, lq = l >> 4;
        uint16_t o[8];
#pragma unroll
        for (int j2 = 0; j2 < 8; ++j2)
            o[j2] = f2bf(W2[(size_t)(c * 32 + lq * 8 + j2) * HS + g * 16 + lr]);
        *(ushort4*)(Bp2 + (size_t)tid * 8)     = *(ushort4*)&o[0];
        *(ushort4*)(Bp2 + (size_t)tid * 8 + 4) = *(ushort4*)&o[4];
    } else if (b < 1824) {
        const int idx = (b - 1536) * 256 + t;            // 0..73727
        out[idx] = (idx < NXS) ? b3[0] : 0.f;
    } else {
        const int idx = (b - 1824) * 256 + t;            // 0..16383
        const int r = idx >> 10, cc = idx & 1023;
        W1T[idx] = (r < 8) ? f2bf(W1[cc * 8 + r]) : (uint16_t)0;
    }
}

// -------- GEMM: R14-verbatim (132.06us total, best measured): 128x128
// tile, 4 waves (2x2), BK=32, TRIPLE-buffered LDS, counted-vmcnt schedule.
//   step c: issue stage(c+2) [4 gload_lds/thread] -> ds_read + 16 MFMA/wave
//   on buf[c%3] -> vmcnt(4) (retire stage(c+1) only; stage(c+2) stays in
//   flight across the barrier) -> raw s_barrier. Peel c>=30 -> vmcnt(0).
// MODE0 epilogue scalars hoisted pre-prologue (keeps vmcnt accounting exact).
// Quarantined (measured): vmcnt(8)-class pipelines (3/3 container kills),
// setprio (R12 -1us..-8us), B-direct-VGPR (R13 +6us).
// R10 counters: MfmaUtil 26%, VALUBusy 35%, stall ~39%, FETCH = compulsory,
// conflicts 0, ~26us/GEMM @ 660 TF.
template <int MODE>
__global__ __launch_bounds__(256, 2) void gemm_k(
    const uint16_t* __restrict__ A, const uint16_t* __restrict__ Bp,
    const float* __restrict__ bias, const float* __restrict__ W3,
    uint16_t* __restrict__ Out, float* __restrict__ yOut,
    const uint16_t* __restrict__ Z1, const uint16_t* __restrict__ W1T,
    float* __restrict__ dOut)
{
    __shared__ __attribute__((aligned(16))) uint16_t smem[24576];  // 48 KB
    const int t = threadIdx.x;
    const int wave = t >> 6, lane = t & 63;
    const int lq = lane >> 4, lr = lane & 15;
    const int wr = wave >> 1, wc = wave & 1;
    const int rowBase = blockIdx.x * 128;
    const int colBase = blockIdx.y * 128;

    // staging sources
    const uint16_t* gA0;
    const uint16_t* gA1;
    {
        int s0 = t,       r0 = s0 >> 2, q0 = (s0 & 3) ^ ((r0 >> 1) & 3);
        int s1 = t + 256, r1 = s1 >> 2, q1 = (s1 & 3) ^ ((r1 >> 1) & 3);
        gA0 = A + (size_t)(rowBase + r0) * HS + q0 * 8;
        gA1 = A + (size_t)(rowBase + r1) * HS + q1 * 8;
    }
    const uint16_t* gB0;
    const uint16_t* gB1;
    {
        int s0 = t, s1 = t + 256;
        gB0 = Bp + ((size_t)(colBase >> 4) + (s0 >> 6)) * 16384 + (size_t)(s0 & 63) * 8;
        gB1 = Bp + ((size_t)(colBase >> 4) + (s1 >> 6)) * 16384 + (size_t)(s1 & 63) * 8;
    }
    const int ldsA0 = t * 16;
    const int ldsA1 = t * 16 + 4096;
    const int ldsB0 = t * 16 + 8192;
    const int ldsB1 = t * 16 + 12288;

    // MODE0 epilogue scalars FIRST (oldest vmem, retired by first wait)
    float cB[4], cW[4]; int cCol[4];
    if (MODE == 0) {
#pragma unroll
        for (int tj = 0; tj < 4; ++tj) {
            cCol[tj] = colBase + wc * 64 + tj * 16 + lr;
            cB[tj] = bias[cCol[tj]];
            cW[tj] = W3[cCol[tj]];
        }
    }

    f32x4 acc[4][4] = {};

    // prologue: stage step 0 -> buf0, step 1 -> buf1
    async_cp16(gA0,        (char*)smem + ldsA0);
    async_cp16(gA1,        (char*)smem + ldsA1);
    async_cp16(gB0,        (char*)smem + ldsB0);
    async_cp16(gB1,        (char*)smem + ldsB1);
    async_cp16(gA0 + 32,   (char*)smem + 16384 + ldsA0);
    async_cp16(gA1 + 32,   (char*)smem + 16384 + ldsA1);
    async_cp16(gB0 + 512,  (char*)smem + 16384 + ldsB0);
    async_cp16(gB1 + 512,  (char*)smem + 16384 + ldsB1);
    gA0 += 64; gA1 += 64; gB0 += 1024; gB1 += 1024;
    asm volatile("s_waitcnt vmcnt(4)" ::: "memory");
    __builtin_amdgcn_s_barrier();

    int rb = 0, wb = 2;
#pragma unroll 1
    for (int c = 0; c < 32; ++c) {
        if (c < 30) {
            char* d = (char*)smem + wb * 16384;
            async_cp16(gA0, d + ldsA0);
            async_cp16(gA1, d + ldsA1);
            async_cp16(gB0, d + ldsB0);
            async_cp16(gB1, d + ldsB1);
            gA0 += 32; gA1 += 32; gB0 += 512; gB1 += 512;
            asm volatile("" ::: "memory");
        }
        const uint16_t* pA  = smem + rb * 8192;
        const uint16_t* pBl = pA + 4096;
        short8 bfrag[4];
#pragma unroll
        for (int tj = 0; tj < 4; ++tj)
            bfrag[tj] = *(const short8*)(pBl + (((wc << 2) + tj) * 64 + lane) * 8);
        short8 af[4];
#pragma unroll
        for (int ti = 0; ti < 4; ++ti) {
            int ar = wr * 64 + ti * 16 + lr;
            af[ti] = *(const short8*)(pA + ar * 32
                      + ((lq ^ ((ar >> 1) & 3)) << 3));
        }
#pragma unroll
        for (int ti = 0; ti < 4; ++ti)
#pragma unroll
            for (int tj = 0; tj < 4; ++tj)
                acc[ti][tj] = __builtin_amdgcn_mfma_f32_16x16x32_bf16(
                    af[ti], bfrag[tj], acc[ti][tj], 0, 0, 0);
        if (c < 30) {
            asm volatile("s_waitcnt vmcnt(4)" ::: "memory");
        } else {
            asm volatile("s_waitcnt vmcnt(0)" ::: "memory");
        }
        __builtin_amdgcn_s_barrier();
        rb = (rb == 2) ? 0 : rb + 1;
        wb = (wb == 2) ? 0 : wb + 1;
    }

    if (MODE == 0) {
#pragma unroll
        for (int ti = 0; ti < 4; ++ti) {
#pragma unroll
            for (int r = 0; r < 4; ++r) {
                int row = rowBase + wr * 64 + ti * 16 + lq * 4 + r;
                float ys = 0.f;
#pragma unroll
                for (int tj = 0; tj < 4; ++tj) {
                    float z2 = fast_tanh(acc[ti][tj][r] + cB[tj]);
                    ys += z2 * cW[tj];
                    Out[(size_t)row * HS + cCol[tj]] = f2bf((1.f - z2 * z2) * cW[tj]);
                }
                ys += __shfl_xor(ys, 1); ys += __shfl_xor(ys, 2);
                ys += __shfl_xor(ys, 4); ys += __shfl_xor(ys, 8);
                if (lr == 0) atomicAdd(&yOut[row], ys);
            }
        }
    } else {
        __builtin_amdgcn_sched_barrier(0);  // fence epilogue vmem below waits
        // c = U*(1-z1^2) -> LDS [128 rows][stride 136 u16]
#pragma unroll
        for (int ti = 0; ti < 4; ++ti)
#pragma unroll
            for (int r = 0; r < 4; ++r) {
                int rowl = wr * 64 + ti * 16 + lq * 4 + r;
                const size_t zrow = (size_t)(rowBase + rowl) * HS + colBase;
#pragma unroll
                for (int tj = 0; tj < 4; ++tj) {
                    int coll = wc * 64 + tj * 16 + lr;
                    float z1 = bf2f(Z1[zrow + coll]);
                    smem[rowl * 136 + coll] =
                        f2bf(acc[ti][tj][r] * (1.f - z1 * z1));
                }
            }
        __syncthreads();
        f32x4 dd[2] = {};
#pragma unroll
        for (int h = 0; h < 2; ++h)
#pragma unroll
            for (int kb = 0; kb < 4; ++kb) {
                short8 aF = *(const short8*)(smem + (wave * 32 + h * 16 + lr) * 136
                                             + kb * 32 + lq * 8);
                short8 bF = *(const short8*)(W1T + (size_t)lr * HS + colBase
                                             + kb * 32 + lq * 8);
                dd[h] = __builtin_amdgcn_mfma_f32_16x16x32_bf16(aF, bF, dd[h], 0, 0, 0);
            }
        if (lr < 8) {
#pragma unroll
            for (int h = 0; h < 2; ++h) {
                int row = rowBase + wave * 32 + h * 16 + lq * 4;
#pragma unroll
                for (int rg = 0; rg < 4; ++rg)
                    atomicAdd(&dOut[(size_t)lr * NXS + row + rg], dd[h][rg]);
            }
        }
    }
}

extern "C" void kernel_launch(void* const* d_in, const int* in_sizes, int n_in,
                              void* d_out, int out_size, void* d_ws, size_t ws_size,
                              hipStream_t stream) {
    (void)in_sizes; (void)n_in; (void)out_size; (void)ws_size;
    const float* x  = (const float*)d_in[0];
    const float* W1 = (const float*)d_in[1];
    const float* b1 = (const float*)d_in[2];
    const float* W2 = (const float*)d_in[3];
    const float* b2 = (const float*)d_in[4];
    const float* W3 = (const float*)d_in[5];
    const float* b3 = (const float*)d_in[6];
    float* out = (float*)d_out;

    char* ws = (char*)d_ws;
    // ws layout:
    //   [0, 16MB)     Z1 bf16        [16MB, 32MB)  V bf16
    //   [32MB, 34MB)  Bp1            [34MB, 36MB)  Bp2
    //   [36MB, +32KB) W1T
    uint16_t* Z1  = (uint16_t*)(ws);
    uint16_t* V   = (uint16_t*)(ws + (size_t)16 * 1024 * 1024);
    uint16_t* Bp1 = (uint16_t*)(ws + (size_t)32 * 1024 * 1024);
    uint16_t* Bp2 = (uint16_t*)(ws + (size_t)34 * 1024 * 1024);
    uint16_t* W1T = (uint16_t*)(ws + (size_t)36 * 1024 * 1024);

    k01<<<1888, 256, 0, stream>>>(x, W1, b1, W2, b3, Z1, Bp1, Bp2, W1T, out);
    gemm_k<0><<<dim3(NXS / 128, HS / 128), 256, 0, stream>>>(
        Z1, Bp1, b2, W3, V, out, nullptr, nullptr, nullptr);
    gemm_k<1><<<dim3(NXS / 128, HS / 128), 256, 0, stream>>>(
        V, Bp2, nullptr, nullptr, nullptr, nullptr, Z1, W1T, out + NXS);
}